// Round 1
// baseline (2706.038 us; speedup 1.0000x reference)
//
#include <hip/hip_runtime.h>
#include <hip/hip_bf16.h>

// Problem constants
#define TB 4
#define TL 512
#define TD 2880
#define TN 64
#define TKH 8     // kv heads
#define TH 64
#define TG 8      // N / K
#define TWIN 128
#define TT (TB*TL)        // 2048 tokens

// ---------------------------------------------------------------------------
// Generic tiled fp32 GEMM + bias: C[MxNc] = A[MxKd] * B[KdxNc] + bias[Nc]
// BM=BN=64, BK=16, 256 threads, 4x4 microtile per thread.
// Requires M%64==0, Nc%64==0, Kd%16==0 (true for all four uses).
// ---------------------------------------------------------------------------
__global__ __launch_bounds__(256) void gemm_bias_kernel(
    const float* __restrict__ A, const float* __restrict__ Bm,
    const float* __restrict__ bias, float* __restrict__ C,
    int M, int Kd, int Nc)
{
  // Row stride 68 floats = 272 B (multiple of 16 B) so float4 LDS reads at
  // [kk][4*t] are aligned; 68%32=4 spreads banks.
  __shared__ float As[16][68];   // As[k][m] (A tile transposed)
  __shared__ float Bs[16][68];   // Bs[k][n]

  const int tid = threadIdx.x;
  const int bm = blockIdx.y * 64;
  const int bn = blockIdx.x * 64;
  const int tx = tid & 15;       // micro col group
  const int ty = tid >> 4;       // micro row group

  const int ar = tid >> 2;             // 0..63 : A row within tile
  const int ac = (tid & 3) << 2;       // 0,4,8,12 : A k offset
  const int br = tid >> 4;             // 0..15 : B k row
  const int bc = (tid & 15) << 2;      // 0..60 : B col offset

  float acc[4][4] = {};

  for (int k0 = 0; k0 < Kd; k0 += 16) {
    float4 av = *reinterpret_cast<const float4*>(&A[(size_t)(bm + ar)*Kd + k0 + ac]);
    float4 bv = *reinterpret_cast<const float4*>(&Bm[(size_t)(k0 + br)*Nc + bn + bc]);
    As[ac+0][ar] = av.x; As[ac+1][ar] = av.y; As[ac+2][ar] = av.z; As[ac+3][ar] = av.w;
    *reinterpret_cast<float4*>(&Bs[br][bc]) = bv;
    __syncthreads();
#pragma unroll
    for (int kk = 0; kk < 16; ++kk) {
      float4 a4 = *reinterpret_cast<const float4*>(&As[kk][ty*4]);
      float4 b4 = *reinterpret_cast<const float4*>(&Bs[kk][tx*4]);
      float a[4] = {a4.x, a4.y, a4.z, a4.w};
      float b[4] = {b4.x, b4.y, b4.z, b4.w};
#pragma unroll
      for (int i = 0; i < 4; ++i)
#pragma unroll
        for (int j = 0; j < 4; ++j) acc[i][j] += a[i]*b[j];
    }
    __syncthreads();
  }

#pragma unroll
  for (int i = 0; i < 4; ++i) {
    const int row = bm + ty*4 + i;
#pragma unroll
    for (int j = 0; j < 4; ++j) {
      const int col = bn + tx*4 + j;
      C[(size_t)row*Nc + col] = acc[i][j] + bias[col];
    }
  }
}

// ---------------------------------------------------------------------------
// YaRN RoPE applied in place to q (TN heads) and k (TKH heads).
// One thread per (t, head, pair i in 0..31).
// ---------------------------------------------------------------------------
__global__ __launch_bounds__(256) void rope_kernel(
    float* __restrict__ q, float* __restrict__ k,
    const int* __restrict__ positions)
{
  const int total = TT*(TN+TKH)*32;
  int idx = blockIdx.x*256 + threadIdx.x;
  if (idx >= total) return;
  const int i    = idx & 31;
  const int rest = idx >> 5;
  const int head = rest % (TN+TKH);
  const int t    = rest / (TN+TKH);

  // constants (double-precision-derived):
  const float lnth = 11.918390573078392f;   // ln(150000)
  const float low  = 8.092779f;             // 32*ln(4096/(64*pi))/ln(theta)
  const float high = 17.398025f;            // 32*ln(4096/(2*pi))/ln(theta)
  const float conc = 1.3465735903f;         // 0.1*ln(32)+1

  const float fi = (float)i * 0.03125f;     // i/32
  const float inv_theta_pow = expf(-fi * lnth);      // 1/freq = theta^(-i/32)
  const float interp = inv_theta_pow * (1.0f/32.0f); // 1/(scaling*freq)
  const float extrap = inv_theta_pow;                // 1/freq
  float ramp = ((float)i - low) * (1.0f/(high - low));
  ramp = fminf(fmaxf(ramp, 0.0f), 1.0f);
  const float inv_freq = interp*ramp + extrap*(1.0f - ramp);

  const float pos = (float)positions[t];
  const float ang = pos * inv_freq;
  const float c = cosf(ang) * conc;
  const float s = sinf(ang) * conc;

  float* base = (head < TN) ? (q + ((size_t)t*TN + head)*TH)
                            : (k + ((size_t)t*TKH + (head - TN))*TH);
  const float x1 = base[i];
  const float x2 = base[i + 32];
  base[i]      = x1*c - x2*s;
  base[i + 32] = x2*c + x1*s;
}

// ---------------------------------------------------------------------------
// Sliding-window causal attention with sinks. One wave (64 lanes) per (t, n).
// lane = h index. Online softmax (wave-uniform scalars). Output written in
// place over the q row (read fully before any write).
// ---------------------------------------------------------------------------
__global__ __launch_bounds__(256) void attn_kernel(
    float* __restrict__ q, const float* __restrict__ kbuf,
    const float* __restrict__ vbuf, const float* __restrict__ sinks)
{
  const int wave = threadIdx.x >> 6;
  const int lane = threadIdx.x & 63;
  const int gw = blockIdx.x*4 + wave;      // 0 .. TT*TN-1
  const int t = gw / TN;
  const int n = gw % TN;
  const int b = t / TL;
  const int l = t % TL;
  const int kh = n / TG;                   // kv head

  float* qrow = q + ((size_t)t*TN + n)*TH;
  const float qv = qrow[lane];

  const int mstart = (l - TWIN + 1 > 0) ? (l - TWIN + 1) : 0;

  float M = -1e30f, den = 0.0f, acc = 0.0f;
  for (int m = mstart; m <= l; ++m) {
    const size_t kvoff = ((size_t)(b*TL + m)*TKH + kh)*TH;
    float prod = qv * kbuf[kvoff + lane];
#pragma unroll
    for (int off = 32; off; off >>= 1) prod += __shfl_xor(prod, off);
    const float s = prod * 0.125f;         // SM_SCALE = 1/sqrt(64)
    const float vv = vbuf[kvoff + lane];
    if (s > M) {                           // wave-uniform branch
      const float scale = __expf(M - s);
      den = den*scale + 1.0f;
      acc = acc*scale + vv;
      M = s;
    } else {
      const float p = __expf(s - M);
      den += p;
      acc += p*vv;
    }
  }
  const float sink = sinks[n];
  const float mf = fmaxf(M, sink);
  const float corr = __expf(M - mf);
  const float dtot = den*corr + __expf(sink - mf);
  qrow[lane] = acc*corr / dtot;
}

// ---------------------------------------------------------------------------
extern "C" void kernel_launch(void* const* d_in, const int* in_sizes, int n_in,
                              void* d_out, int out_size, void* d_ws, size_t ws_size,
                              hipStream_t stream)
{
  const float* x     = (const float*)d_in[0];
  const float* wq    = (const float*)d_in[1];   // (D, N*H) row-major when flat
  const float* bq    = (const float*)d_in[2];   // (N*H)
  const float* wk    = (const float*)d_in[3];   // (D, K*H)
  const float* bk    = (const float*)d_in[4];
  const float* wv    = (const float*)d_in[5];
  const float* bv    = (const float*)d_in[6];
  const float* wo    = (const float*)d_in[7];   // (N*H, D) row-major when flat
  const float* bo    = (const float*)d_in[8];
  const float* sinks = (const float*)d_in[9];
  const int* positions = (const int*)d_in[10];
  float* out = (float*)d_out;

  float* qbuf = (float*)d_ws;                       // TT*TN*TH  (also attn out)
  float* kbuf = qbuf + (size_t)TT*TN*TH;            // TT*TKH*TH
  float* vbuf = kbuf + (size_t)TT*TKH*TH;           // TT*TKH*TH

  dim3 blk(256);

  // QKV projections
  gemm_bias_kernel<<<dim3((TN*TH)/64, TT/64), blk, 0, stream>>>(
      x, wq, bq, qbuf, TT, TD, TN*TH);
  gemm_bias_kernel<<<dim3((TKH*TH)/64, TT/64), blk, 0, stream>>>(
      x, wk, bk, kbuf, TT, TD, TKH*TH);
  gemm_bias_kernel<<<dim3((TKH*TH)/64, TT/64), blk, 0, stream>>>(
      x, wv, bv, vbuf, TT, TD, TKH*TH);

  // RoPE on q and k (in place)
  const int rope_total = TT*(TN+TKH)*32;
  rope_kernel<<<(rope_total + 255)/256, blk, 0, stream>>>(qbuf, kbuf, positions);

  // Attention (writes o over qbuf)
  attn_kernel<<<(TT*TN)/4, blk, 0, stream>>>(qbuf, kbuf, vbuf, sinks);

  // Output projection
  gemm_bias_kernel<<<dim3(TD/64, TT/64), blk, 0, stream>>>(
      qbuf, wo, bo, out, TT, TN*TH, TD);
}

// Round 2
// 386.333 us; speedup vs baseline: 7.0044x; 7.0044x over previous
//
#include <hip/hip_runtime.h>
#include <hip/hip_bf16.h>

#define TB 4
#define TL 512
#define TD 2880
#define TN 64
#define TKH 8
#define TH 64
#define TG 8
#define TWIN 128
#define TT (TB*TL)

typedef unsigned short u16;
typedef __attribute__((ext_vector_type(8))) short bf16x8;
typedef __attribute__((ext_vector_type(4))) float f32x4;

__device__ __forceinline__ u16 f2b(float f) {
  unsigned u = __float_as_uint(f);
  u += 0x7fffu + ((u >> 16) & 1u);
  return (u16)(u >> 16);
}
__device__ __forceinline__ float b2f(u16 u) {
  return __uint_as_float(((unsigned)u) << 16);
}

__device__ __forceinline__ void load_lds16(const u16* g, u16* l) {
  __builtin_amdgcn_global_load_lds(
      (const __attribute__((address_space(1))) unsigned int*)g,
      (__attribute__((address_space(3))) unsigned int*)l, 16, 0, 0);
}

// ---------------------------------------------------------------------------
// bf16 MFMA GEMM: C[M x Nc] = A[M x Kd] * Bt^T + bias, Bt is [Ncpad][Kd]
// (B stored transposed, row-major by output column). 128x128 tile, BK=32,
// 256 threads (4 waves 2x2), each wave 64x64 via 4x4 frags of 16x16x32.
// ---------------------------------------------------------------------------
__global__ __launch_bounds__(256) void gemm_mfma(
    const u16* __restrict__ A, const u16* __restrict__ Bt,
    const float* __restrict__ bias, void* __restrict__ Cv,
    int Kd, int Nc, int ldc, int out_bf16)
{
  __shared__ u16 As[128*32];   // [row][k], row stride 32
  __shared__ u16 Bs[128*32];   // [col][k]

  const int tid  = threadIdx.x;
  const int lane = tid & 63;
  const int wave = tid >> 6;
  const int bm = blockIdx.y * 128, bn = blockIdx.x * 128;
  const int wr = (wave >> 1) * 64, wc = (wave & 1) * 64;

  f32x4 acc[4][4];
#pragma unroll
  for (int i = 0; i < 4; ++i)
#pragma unroll
    for (int j = 0; j < 4; ++j) acc[i][j] = (f32x4){0.f, 0.f, 0.f, 0.f};

  // staging: slot f = j*256 + tid -> row = f>>2, k8 = (f&3)*8, 16B per lane
  const int r0 = tid >> 2, k80 = (tid & 3) * 8;
  const u16* a0 = A  + (size_t)(bm + r0)      * Kd + k80;
  const u16* a1 = A  + (size_t)(bm + r0 + 64) * Kd + k80;
  const u16* b0 = Bt + (size_t)(bn + r0)      * Kd + k80;
  const u16* b1 = Bt + (size_t)(bn + r0 + 64) * Kd + k80;
  u16* as0 = &As[wave*64*8];
  u16* as1 = &As[(256 + wave*64)*8];
  u16* bs0 = &Bs[wave*64*8];
  u16* bs1 = &Bs[(256 + wave*64)*8];

  const int fr = lane & 15, fk = (lane >> 4) * 8;

  for (int k0 = 0; k0 < Kd; k0 += 32) {
    load_lds16(a0 + k0, as0);
    load_lds16(a1 + k0, as1);
    load_lds16(b0 + k0, bs0);
    load_lds16(b1 + k0, bs1);
    __syncthreads();
    bf16x8 af[4], bfv[4];
#pragma unroll
    for (int mi = 0; mi < 4; ++mi)
      af[mi] = *(const bf16x8*)&As[(wr + mi*16 + fr)*32 + fk];
#pragma unroll
    for (int ni = 0; ni < 4; ++ni)
      bfv[ni] = *(const bf16x8*)&Bs[(wc + ni*16 + fr)*32 + fk];
#pragma unroll
    for (int mi = 0; mi < 4; ++mi)
#pragma unroll
      for (int ni = 0; ni < 4; ++ni)
        acc[mi][ni] = __builtin_amdgcn_mfma_f32_16x16x32_bf16(
            af[mi], bfv[ni], acc[mi][ni], 0, 0, 0);
    __syncthreads();
  }

  // epilogue: C/D layout col=lane&15, row=(lane>>4)*4+j
  const int rbase = bm + wr + (lane >> 4) * 4;
  const int cbase = bn + wc + (lane & 15);
#pragma unroll
  for (int mi = 0; mi < 4; ++mi) {
#pragma unroll
    for (int ni = 0; ni < 4; ++ni) {
      const int col = cbase + ni*16;
      const float bv = (col < Nc) ? bias[col] : 0.f;
#pragma unroll
      for (int j = 0; j < 4; ++j) {
        const int row = rbase + mi*16 + j;
        const float val = acc[mi][ni][j] + bv;
        if (out_bf16) {
          ((u16*)Cv)[(size_t)row*ldc + col] = f2b(val);
        } else if (col < Nc) {
          ((float*)Cv)[(size_t)row*ldc + col] = val;
        }
      }
    }
  }
}

// ---------------------------------------------------------------------------
// fp32 -> bf16 elementwise convert (x)
// ---------------------------------------------------------------------------
__global__ __launch_bounds__(256) void cvt4_kernel(
    const float* __restrict__ in, u16* __restrict__ out, int n4)
{
  int i = blockIdx.x*256 + threadIdx.x;
  if (i < n4) {
    float4 f = ((const float4*)in)[i];
    ushort4 o;
    o.x = f2b(f.x); o.y = f2b(f.y); o.z = f2b(f.z); o.w = f2b(f.w);
    ((ushort4*)out)[i] = o;
  }
}

// ---------------------------------------------------------------------------
// transpose + convert: in fp32 [R][C] -> out bf16 [C][R].  32x32 LDS tile.
// ---------------------------------------------------------------------------
__global__ __launch_bounds__(256) void tconv_kernel(
    const float* __restrict__ in, u16* __restrict__ out, int R, int C)
{
  __shared__ float tile[32][33];
  const int c0 = blockIdx.x*32, r0 = blockIdx.y*32;
  const int tx = threadIdx.x & 31, ty = threadIdx.x >> 5;
#pragma unroll
  for (int i = 0; i < 4; ++i)
    tile[ty + i*8][tx] = in[(size_t)(r0 + ty + i*8)*C + c0 + tx];
  __syncthreads();
#pragma unroll
  for (int i = 0; i < 4; ++i) {
    const int oc = ty + i*8;
    out[(size_t)(c0 + oc)*R + r0 + tx] = f2b(tile[tx][oc]);
  }
}

__global__ __launch_bounds__(256) void zerofill_kernel(u16* p, int n4)
{
  int i = blockIdx.x*256 + threadIdx.x;
  if (i < n4) ((ushort4*)p)[i] = (ushort4){0,0,0,0};
}

__global__ __launch_bounds__(256) void biascat_kernel(
    const float* __restrict__ bq, const float* __restrict__ bk,
    const float* __restrict__ bv, float* __restrict__ o)
{
  int i = blockIdx.x*256 + threadIdx.x;
  if (i < 5120)
    o[i] = (i < 4096) ? bq[i] : (i < 4608 ? bk[i-4096] : bv[i-4608]);
}

// ---------------------------------------------------------------------------
// YaRN RoPE in place on bf16 qkv buffer [TT][5120]: q cols 0..4095, k 4096..4607
// ---------------------------------------------------------------------------
__global__ __launch_bounds__(256) void rope_bf16_kernel(
    u16* __restrict__ qkv, const int* __restrict__ positions)
{
  const int total = TT*(TN+TKH)*32;
  int idx = blockIdx.x*256 + threadIdx.x;
  if (idx >= total) return;
  const int i    = idx & 31;
  const int rest = idx >> 5;
  const int head = rest % (TN+TKH);
  const int t    = rest / (TN+TKH);

  const float lnth = 11.918390573078392f;
  const float low  = 8.092779f;
  const float high = 17.398025f;
  const float conc = 1.3465735903f;

  const float fi = (float)i * 0.03125f;
  const float inv_theta_pow = __expf(-fi * lnth);
  const float interp = inv_theta_pow * (1.0f/32.0f);
  const float extrap = inv_theta_pow;
  float ramp = ((float)i - low) * (1.0f/(high - low));
  ramp = fminf(fmaxf(ramp, 0.0f), 1.0f);
  const float inv_freq = interp*ramp + extrap*(1.0f - ramp);

  const float ang = (float)positions[t] * inv_freq;
  const float c = cosf(ang) * conc;
  const float s = sinf(ang) * conc;

  const int col = (head < TN) ? head*64 : 4096 + (head - TN)*64;
  u16* base = qkv + (size_t)t*5120 + col;
  const float x1 = b2f(base[i]);
  const float x2 = b2f(base[i + 32]);
  base[i]      = f2b(x1*c - x2*s);
  base[i + 32] = f2b(x2*c + x1*s);
}

// ---------------------------------------------------------------------------
// Attention v2: one block per (t, kh). K/V window staged in LDS (bf16,
// stride-68 rows). Phase 1: thread (g, ml) computes scores for 4 m's,
// group softmax via 5-step shfl. Phase 2: P.V with p from LDS.
// Output: bf16 obuf [TT][4096].
// ---------------------------------------------------------------------------
__global__ __launch_bounds__(256) void attn2_kernel(
    const u16* __restrict__ qkv, u16* __restrict__ obuf,
    const float* __restrict__ sinks)
{
  __shared__ u16 Kl[128*68];
  __shared__ u16 Vl[128*68];
  __shared__ float pl[8*128];

  const int t = blockIdx.x, kh = blockIdx.y;
  const int l = t & (TL-1), b = t >> 9;
  const int mstart = (l - TWIN + 1 > 0) ? (l - TWIN + 1) : 0;
  const int mcount = l - mstart + 1;
  const int tid = threadIdx.x;
  const int g = tid >> 5, ml = tid & 31;

  // q row for this thread's head into registers (broadcast loads)
  float qreg[64];
  {
    const u16* qrow = qkv + (size_t)t*5120 + (kh*8+g)*64;
#pragma unroll
    for (int s2 = 0; s2 < 8; ++s2) {
      uint4 qa = *(const uint4*)(qrow + s2*8);
      qreg[s2*8+0] = __uint_as_float(qa.x << 16);
      qreg[s2*8+1] = __uint_as_float(qa.x & 0xffff0000u);
      qreg[s2*8+2] = __uint_as_float(qa.y << 16);
      qreg[s2*8+3] = __uint_as_float(qa.y & 0xffff0000u);
      qreg[s2*8+4] = __uint_as_float(qa.z << 16);
      qreg[s2*8+5] = __uint_as_float(qa.z & 0xffff0000u);
      qreg[s2*8+6] = __uint_as_float(qa.w << 16);
      qreg[s2*8+7] = __uint_as_float(qa.w & 0xffff0000u);
    }
  }

  // stage K and V windows (bf16 copy, padded stride 68)
  {
    const u16* kb = qkv + (size_t)(b*TL + mstart)*5120 + 4096 + kh*64;
    for (int s = tid; s < mcount*8; s += 256) {
      const int row = s >> 3, seg = s & 7;
      const u16* gk = kb + (size_t)row*5120 + seg*8;
      uint4 k4 = *(const uint4*)gk;
      uint4 v4 = *(const uint4*)(gk + 512);
      *(uint2*)&Kl[row*68 + seg*8]     = make_uint2(k4.x, k4.y);
      *(uint2*)&Kl[row*68 + seg*8 + 4] = make_uint2(k4.z, k4.w);
      *(uint2*)&Vl[row*68 + seg*8]     = make_uint2(v4.x, v4.y);
      *(uint2*)&Vl[row*68 + seg*8 + 4] = make_uint2(v4.z, v4.w);
    }
  }
  __syncthreads();

  // phase 1: scores + softmax
  float sv[4];
#pragma unroll
  for (int mi = 0; mi < 4; ++mi) {
    const int m = ml + mi*32;
    float acc = -1e30f;
    if (m < mcount) {
      float d = 0.f;
#pragma unroll
      for (int h4 = 0; h4 < 16; ++h4) {
        ushort4 kv = *(const ushort4*)&Kl[m*68 + h4*4];
        d += b2f(kv.x)*qreg[h4*4+0] + b2f(kv.y)*qreg[h4*4+1]
           + b2f(kv.z)*qreg[h4*4+2] + b2f(kv.w)*qreg[h4*4+3];
      }
      acc = d * 0.125f;   // 1/sqrt(64)
    }
    sv[mi] = acc;
  }
  float mx = fmaxf(fmaxf(sv[0], sv[1]), fmaxf(sv[2], sv[3]));
#pragma unroll
  for (int off = 16; off; off >>= 1) mx = fmaxf(mx, __shfl_xor(mx, off));
  const float sink = sinks[kh*8+g];
  const float M = fmaxf(mx, sink);
  float p[4], dl = 0.f;
#pragma unroll
  for (int mi = 0; mi < 4; ++mi) {
    p[mi] = (sv[mi] > -1e29f) ? __expf(sv[mi] - M) : 0.f;
    dl += p[mi];
  }
#pragma unroll
  for (int off = 16; off; off >>= 1) dl += __shfl_xor(dl, off);
  const float inv = 1.0f / (dl + __expf(sink - M));
#pragma unroll
  for (int mi = 0; mi < 4; ++mi) {
    const int m = ml + mi*32;
    if (m < mcount) pl[g*128 + m] = p[mi] * inv;
  }
  __syncthreads();

  // phase 2: o = P . V   (thread = (g, h4, mhalf))
  const int h4 = ml & 15, mh = ml >> 4;
  float ox = 0.f, oy = 0.f, oz = 0.f, ow = 0.f;
  for (int m = mh; m < mcount; m += 2) {
    const float pw = pl[g*128 + m];
    ushort4 vv = *(const ushort4*)&Vl[m*68 + h4*4];
    ox += pw * b2f(vv.x);
    oy += pw * b2f(vv.y);
    oz += pw * b2f(vv.z);
    ow += pw * b2f(vv.w);
  }
  ox += __shfl_xor(ox, 16);
  oy += __shfl_xor(oy, 16);
  oz += __shfl_xor(oz, 16);
  ow += __shfl_xor(ow, 16);
  if (mh == 0) {
    ushort4 o4;
    o4.x = f2b(ox); o4.y = f2b(oy); o4.z = f2b(oz); o4.w = f2b(ow);
    *(ushort4*)&obuf[(size_t)t*4096 + (kh*8+g)*64 + h4*4] = o4;
  }
}

// ===========================================================================
// Fallback fp32 path (round-1 proven) — used if workspace is too small.
// ===========================================================================
__global__ __launch_bounds__(256) void gemm_bias_kernel(
    const float* __restrict__ A, const float* __restrict__ Bm,
    const float* __restrict__ bias, float* __restrict__ C,
    int M, int Kd, int Nc)
{
  __shared__ float As0[16][68];
  __shared__ float Bs0[16][68];
  const int tid = threadIdx.x;
  const int bm = blockIdx.y * 64;
  const int bn = blockIdx.x * 64;
  const int tx = tid & 15, ty = tid >> 4;
  const int ar = tid >> 2, ac = (tid & 3) << 2;
  const int br = tid >> 4, bc = (tid & 15) << 2;
  float acc[4][4] = {};
  for (int k0 = 0; k0 < Kd; k0 += 16) {
    float4 av = *reinterpret_cast<const float4*>(&A[(size_t)(bm + ar)*Kd + k0 + ac]);
    float4 bv = *reinterpret_cast<const float4*>(&Bm[(size_t)(k0 + br)*Nc + bn + bc]);
    As0[ac+0][ar] = av.x; As0[ac+1][ar] = av.y; As0[ac+2][ar] = av.z; As0[ac+3][ar] = av.w;
    *reinterpret_cast<float4*>(&Bs0[br][bc]) = bv;
    __syncthreads();
#pragma unroll
    for (int kk = 0; kk < 16; ++kk) {
      float4 a4 = *reinterpret_cast<const float4*>(&As0[kk][ty*4]);
      float4 b4 = *reinterpret_cast<const float4*>(&Bs0[kk][tx*4]);
      float a[4] = {a4.x, a4.y, a4.z, a4.w};
      float b[4] = {b4.x, b4.y, b4.z, b4.w};
#pragma unroll
      for (int i = 0; i < 4; ++i)
#pragma unroll
        for (int j = 0; j < 4; ++j) acc[i][j] += a[i]*b[j];
    }
    __syncthreads();
  }
#pragma unroll
  for (int i = 0; i < 4; ++i) {
    const int row = bm + ty*4 + i;
#pragma unroll
    for (int j = 0; j < 4; ++j) {
      const int col = bn + tx*4 + j;
      C[(size_t)row*Nc + col] = acc[i][j] + bias[col];
    }
  }
}

__global__ __launch_bounds__(256) void rope_f32_kernel(
    float* __restrict__ q, float* __restrict__ k,
    const int* __restrict__ positions)
{
  const int total = TT*(TN+TKH)*32;
  int idx = blockIdx.x*256 + threadIdx.x;
  if (idx >= total) return;
  const int i    = idx & 31;
  const int rest = idx >> 5;
  const int head = rest % (TN+TKH);
  const int t    = rest / (TN+TKH);
  const float lnth = 11.918390573078392f;
  const float low  = 8.092779f;
  const float high = 17.398025f;
  const float conc = 1.3465735903f;
  const float fi = (float)i * 0.03125f;
  const float inv_theta_pow = expf(-fi * lnth);
  const float interp = inv_theta_pow * (1.0f/32.0f);
  const float extrap = inv_theta_pow;
  float ramp = ((float)i - low) * (1.0f/(high - low));
  ramp = fminf(fmaxf(ramp, 0.0f), 1.0f);
  const float inv_freq = interp*ramp + extrap*(1.0f - ramp);
  const float ang = (float)positions[t] * inv_freq;
  const float c = cosf(ang) * conc;
  const float s = sinf(ang) * conc;
  float* base = (head < TN) ? (q + ((size_t)t*TN + head)*TH)
                            : (k + ((size_t)t*TKH + (head - TN))*TH);
  const float x1 = base[i];
  const float x2 = base[i + 32];
  base[i]      = x1*c - x2*s;
  base[i + 32] = x2*c + x1*s;
}

__global__ __launch_bounds__(256) void attn_kernel(
    float* __restrict__ q, const float* __restrict__ kbuf,
    const float* __restrict__ vbuf, const float* __restrict__ sinks)
{
  const int wave = threadIdx.x >> 6;
  const int lane = threadIdx.x & 63;
  const int gw = blockIdx.x*4 + wave;
  const int t = gw / TN;
  const int n = gw % TN;
  const int b = t / TL;
  const int l = t % TL;
  const int kh = n / TG;
  float* qrow = q + ((size_t)t*TN + n)*TH;
  const float qv = qrow[lane];
  const int mstart = (l - TWIN + 1 > 0) ? (l - TWIN + 1) : 0;
  float M = -1e30f, den = 0.0f, acc = 0.0f;
  for (int m = mstart; m <= l; ++m) {
    const size_t kvoff = ((size_t)(b*TL + m)*TKH + kh)*TH;
    float prod = qv * kbuf[kvoff + lane];
#pragma unroll
    for (int off = 32; off; off >>= 1) prod += __shfl_xor(prod, off);
    const float s = prod * 0.125f;
    const float vv = vbuf[kvoff + lane];
    if (s > M) {
      const float scale = __expf(M - s);
      den = den*scale + 1.0f;
      acc = acc*scale + vv;
      M = s;
    } else {
      const float p = __expf(s - M);
      den += p;
      acc += p*vv;
    }
  }
  const float sink = sinks[n];
  const float mf = fmaxf(M, sink);
  const float corr = __expf(M - mf);
  const float dtot = den*corr + __expf(sink - mf);
  qrow[lane] = acc*corr / dtot;
}

// ---------------------------------------------------------------------------
extern "C" void kernel_launch(void* const* d_in, const int* in_sizes, int n_in,
                              void* d_out, int out_size, void* d_ws, size_t ws_size,
                              hipStream_t stream)
{
  const float* x     = (const float*)d_in[0];
  const float* wq    = (const float*)d_in[1];
  const float* bq    = (const float*)d_in[2];
  const float* wk    = (const float*)d_in[3];
  const float* bk    = (const float*)d_in[4];
  const float* wv    = (const float*)d_in[5];
  const float* bv    = (const float*)d_in[6];
  const float* wo    = (const float*)d_in[7];
  const float* bo    = (const float*)d_in[8];
  const float* sinks = (const float*)d_in[9];
  const int* positions = (const int*)d_in[10];
  float* out = (float*)d_out;

  // new-path workspace layout (bytes): 103,174,144
  const size_t NEED = ((size_t)TT*TD + (size_t)5120*TD + (size_t)2944*4096 +
                       (size_t)TT*5120 + (size_t)TT*4096) * 2 + 5120*4 + 256;

  if (ws_size >= NEED) {
    u16* xb    = (u16*)d_ws;
    u16* wqkvt = xb + (size_t)TT*TD;
    u16* wot   = wqkvt + (size_t)5120*TD;
    u16* qkv   = wot + (size_t)2944*4096;
    u16* obuf  = qkv + (size_t)TT*5120;
    float* bqkv = (float*)(obuf + (size_t)TT*4096);

    // converts / transposes
    cvt4_kernel<<<(TT*TD/4 + 255)/256, 256, 0, stream>>>(x, xb, TT*TD/4);
    tconv_kernel<<<dim3(128, 90), 256, 0, stream>>>(wq, wqkvt, TD, 4096);
    tconv_kernel<<<dim3(16, 90), 256, 0, stream>>>(wk, wqkvt + (size_t)4096*TD, TD, 512);
    tconv_kernel<<<dim3(16, 90), 256, 0, stream>>>(wv, wqkvt + (size_t)4608*TD, TD, 512);
    tconv_kernel<<<dim3(90, 128), 256, 0, stream>>>(wo, wot, 4096, TD);
    zerofill_kernel<<<(64*4096/4 + 255)/256, 256, 0, stream>>>(
        wot + (size_t)2880*4096, 64*4096/4);
    biascat_kernel<<<20, 256, 0, stream>>>(bq, bk, bv, bqkv);

    // fused QKV projection: [2048 x 2880] x [2880 x 5120] -> bf16 qkv
    gemm_mfma<<<dim3(40, 16), 256, 0, stream>>>(
        xb, wqkvt, bqkv, qkv, TD, 5120, 5120, 1);

    // RoPE in place on q,k columns
    rope_bf16_kernel<<<(TT*(TN+TKH)*32 + 255)/256, 256, 0, stream>>>(qkv, positions);

    // attention
    attn2_kernel<<<dim3(TT, TKH), 256, 0, stream>>>(qkv, obuf, sinks);

    // output projection: [2048 x 4096] x [4096 x 2880] -> fp32 out
    gemm_mfma<<<dim3(23, 16), 256, 0, stream>>>(
        obuf, wot, bo, out, 4096, 2880, 2880, 0);
  } else {
    // fallback fp32 path
    float* qbuf = (float*)d_ws;
    float* kbuf = qbuf + (size_t)TT*TN*TH;
    float* vbuf = kbuf + (size_t)TT*TKH*TH;
    dim3 blk(256);
    gemm_bias_kernel<<<dim3((TN*TH)/64, TT/64), blk, 0, stream>>>(
        x, wq, bq, qbuf, TT, TD, TN*TH);
    gemm_bias_kernel<<<dim3((TKH*TH)/64, TT/64), blk, 0, stream>>>(
        x, wk, bk, kbuf, TT, TD, TKH*TH);
    gemm_bias_kernel<<<dim3((TKH*TH)/64, TT/64), blk, 0, stream>>>(
        x, wv, bv, vbuf, TT, TD, TKH*TH);
    const int rope_total = TT*(TN+TKH)*32;
    rope_f32_kernel<<<(rope_total + 255)/256, blk, 0, stream>>>(qbuf, kbuf, positions);
    attn_kernel<<<(TT*TN)/4, blk, 0, stream>>>(qbuf, kbuf, vbuf, sinks);
    gemm_bias_kernel<<<dim3(TD/64, TT/64), blk, 0, stream>>>(
        qbuf, wo, bo, out, TT, TN*TH, TD);
  }
}

// Round 4
// 275.086 us; speedup vs baseline: 9.8371x; 1.4044x over previous
//
#include <hip/hip_runtime.h>
#include <hip/hip_bf16.h>

#define TB 4
#define TL 512
#define TD 2880
#define TN 64
#define TKH 8
#define TH 64
#define TG 8
#define TWIN 128
#define TT (TB*TL)

typedef unsigned short u16;
typedef __attribute__((ext_vector_type(8))) short bf16x8;
typedef __attribute__((ext_vector_type(4))) float f32x4;

__device__ __forceinline__ u16 f2b(float f) {
  unsigned u = __float_as_uint(f);
  u += 0x7fffu + ((u >> 16) & 1u);
  return (u16)(u >> 16);
}
__device__ __forceinline__ float b2f(u16 u) {
  return __uint_as_float(((unsigned)u) << 16);
}

__device__ __forceinline__ void load_lds16(const u16* g, u16* l) {
  __builtin_amdgcn_global_load_lds(
      (const __attribute__((address_space(1))) unsigned int*)g,
      (__attribute__((address_space(3))) unsigned int*)l, 16, 0, 0);
}

// ---------------------------------------------------------------------------
// bf16 MFMA GEMM (unchanged, verified R2): C = A * Bt^T + bias
// ---------------------------------------------------------------------------
__global__ __launch_bounds__(256) void gemm_mfma(
    const u16* __restrict__ A, const u16* __restrict__ Bt,
    const float* __restrict__ bias, void* __restrict__ Cv,
    int Kd, int Nc, int ldc, int out_bf16)
{
  __shared__ u16 As[128*32];
  __shared__ u16 Bs[128*32];

  const int tid  = threadIdx.x;
  const int lane = tid & 63;
  const int wave = tid >> 6;
  const int bm = blockIdx.y * 128, bn = blockIdx.x * 128;
  const int wr = (wave >> 1) * 64, wc = (wave & 1) * 64;

  f32x4 acc[4][4];
#pragma unroll
  for (int i = 0; i < 4; ++i)
#pragma unroll
    for (int j = 0; j < 4; ++j) acc[i][j] = (f32x4){0.f, 0.f, 0.f, 0.f};

  const int r0 = tid >> 2, k80 = (tid & 3) * 8;
  const u16* a0 = A  + (size_t)(bm + r0)      * Kd + k80;
  const u16* a1 = A  + (size_t)(bm + r0 + 64) * Kd + k80;
  const u16* b0 = Bt + (size_t)(bn + r0)      * Kd + k80;
  const u16* b1 = Bt + (size_t)(bn + r0 + 64) * Kd + k80;
  u16* as0 = &As[wave*64*8];
  u16* as1 = &As[(256 + wave*64)*8];
  u16* bs0 = &Bs[wave*64*8];
  u16* bs1 = &Bs[(256 + wave*64)*8];

  const int fr = lane & 15, fk = (lane >> 4) * 8;

  for (int k0 = 0; k0 < Kd; k0 += 32) {
    load_lds16(a0 + k0, as0);
    load_lds16(a1 + k0, as1);
    load_lds16(b0 + k0, bs0);
    load_lds16(b1 + k0, bs1);
    __syncthreads();
    bf16x8 af[4], bfv[4];
#pragma unroll
    for (int mi = 0; mi < 4; ++mi)
      af[mi] = *(const bf16x8*)&As[(wr + mi*16 + fr)*32 + fk];
#pragma unroll
    for (int ni = 0; ni < 4; ++ni)
      bfv[ni] = *(const bf16x8*)&Bs[(wc + ni*16 + fr)*32 + fk];
#pragma unroll
    for (int mi = 0; mi < 4; ++mi)
#pragma unroll
      for (int ni = 0; ni < 4; ++ni)
        acc[mi][ni] = __builtin_amdgcn_mfma_f32_16x16x32_bf16(
            af[mi], bfv[ni], acc[mi][ni], 0, 0, 0);
    __syncthreads();
  }

  const int rbase = bm + wr + (lane >> 4) * 4;
  const int cbase = bn + wc + (lane & 15);
#pragma unroll
  for (int mi = 0; mi < 4; ++mi) {
#pragma unroll
    for (int ni = 0; ni < 4; ++ni) {
      const int col = cbase + ni*16;
      const float bv = (col < Nc) ? bias[col] : 0.f;
#pragma unroll
      for (int j = 0; j < 4; ++j) {
        const int row = rbase + mi*16 + j;
        const float val = acc[mi][ni][j] + bv;
        if (out_bf16) {
          ((u16*)Cv)[(size_t)row*ldc + col] = f2b(val);
        } else if (col < Nc) {
          ((float*)Cv)[(size_t)row*ldc + col] = val;
        }
      }
    }
  }
}

__global__ __launch_bounds__(256) void cvt4_kernel(
    const float* __restrict__ in, u16* __restrict__ out, int n4)
{
  int i = blockIdx.x*256 + threadIdx.x;
  if (i < n4) {
    float4 f = ((const float4*)in)[i];
    ushort4 o;
    o.x = f2b(f.x); o.y = f2b(f.y); o.z = f2b(f.z); o.w = f2b(f.w);
    ((ushort4*)out)[i] = o;
  }
}

__global__ __launch_bounds__(256) void tconv_kernel(
    const float* __restrict__ in, u16* __restrict__ out, int R, int C)
{
  __shared__ float tile[32][33];
  const int c0 = blockIdx.x*32, r0 = blockIdx.y*32;
  const int tx = threadIdx.x & 31, ty = threadIdx.x >> 5;
#pragma unroll
  for (int i = 0; i < 4; ++i)
    tile[ty + i*8][tx] = in[(size_t)(r0 + ty + i*8)*C + c0 + tx];
  __syncthreads();
#pragma unroll
  for (int i = 0; i < 4; ++i) {
    const int oc = ty + i*8;
    out[(size_t)(c0 + oc)*R + r0 + tx] = f2b(tile[tx][oc]);
  }
}

__global__ __launch_bounds__(256) void zerofill_kernel(u16* p, int n4)
{
  int i = blockIdx.x*256 + threadIdx.x;
  if (i < n4) ((ushort4*)p)[i] = (ushort4){0,0,0,0};
}

__global__ __launch_bounds__(256) void biascat_kernel(
    const float* __restrict__ bq, const float* __restrict__ bk,
    const float* __restrict__ bv, float* __restrict__ o)
{
  int i = blockIdx.x*256 + threadIdx.x;
  if (i < 5120)
    o[i] = (i < 4096) ? bq[i] : (i < 4608 ? bk[i-4096] : bv[i-4608]);
}

// ---------------------------------------------------------------------------
// YaRN RoPE in place on bf16 qkv [TT][5120]. SM_SCALE pre-folded into q.
// ---------------------------------------------------------------------------
__global__ __launch_bounds__(256) void rope_bf16_kernel(
    u16* __restrict__ qkv, const int* __restrict__ positions)
{
  const int total = TT*(TN+TKH)*32;
  int idx = blockIdx.x*256 + threadIdx.x;
  if (idx >= total) return;
  const int i    = idx & 31;
  const int rest = idx >> 5;
  const int head = rest % (TN+TKH);
  const int t    = rest / (TN+TKH);

  const float lnth = 11.918390573078392f;
  const float low  = 8.092779f;
  const float high = 17.398025f;
  const float conc = 1.3465735903f;

  const float fi = (float)i * 0.03125f;
  const float inv_theta_pow = __expf(-fi * lnth);
  const float interp = inv_theta_pow * (1.0f/32.0f);
  const float extrap = inv_theta_pow;
  float ramp = ((float)i - low) * (1.0f/(high - low));
  ramp = fminf(fmaxf(ramp, 0.0f), 1.0f);
  const float inv_freq = interp*ramp + extrap*(1.0f - ramp);

  const float ang = (float)positions[t] * inv_freq;
  const float mul = (head < TN) ? (conc * 0.125f) : conc;
  const float c = cosf(ang) * mul;
  const float s = sinf(ang) * mul;

  const int col = (head < TN) ? head*64 : 4096 + (head - TN)*64;
  u16* base = qkv + (size_t)t*5120 + col;
  const float x1 = b2f(base[i]);
  const float x2 = b2f(base[i + 32]);
  base[i]      = f2b(x1*c - x2*s);
  base[i + 32] = f2b(x2*c + x1*s);
}

// ---------------------------------------------------------------------------
// MFMA flash attention. Block = (lt, kh, b), 8 waves, wave = GQA head g.
// FIX vs R3: head column is (kh*8+g)*64 in BOTH the Q load and O store
// (R3 used g*64 — wrong head read + cross-kh write races).
// ---------------------------------------------------------------------------
__global__ __launch_bounds__(512) void attn3_kernel(
    const u16* __restrict__ qkv, u16* __restrict__ obuf,
    const float* __restrict__ sinks)
{
  __shared__ u16 Kl[192*64];     // 24 KB
  __shared__ u16 Vt[64*192];     // 24 KB
  __shared__ u16 Pl[8][2048];    // 32 KB (per-wave 64l x 32m)

  const int lt = blockIdx.x, kh = blockIdx.y, b = blockIdx.z;
  const int l0 = lt*64;
  const int mstart = (l0 > 127) ? (l0 - 127) : 0;
  const int mcnt = l0 + 64 - mstart;          // <= 191
  const int NC = (mcnt + 31) >> 5;
  const int base = l0 - mstart;               // 0..127

  const int tid = threadIdx.x;
  const int lane = tid & 63;
  const int g = tid >> 6;
  const int lL = lane & 15;
  const int q = lane >> 4;

  // ---- stage K (swizzled rows) and V transposed (swizzled) ----
  {
    const u16* kv0 = qkv + ((size_t)(b*TL + mstart)*5120 + 4096 + kh*64);
    for (int s = tid; s < 1536; s += 512) {
      const int m = s >> 3, hs = s & 7;
      uint4 kx = make_uint4(0,0,0,0), vx = make_uint4(0,0,0,0);
      if (m < mcnt) {
        const u16* gp = kv0 + (size_t)m*5120 + hs*8;
        kx = *(const uint4*)gp;
        vx = *(const uint4*)(gp + 512);
      }
      *(uint4*)((char*)&Kl[m*64] + ((hs*16) ^ ((m&7)<<4))) = kx;
      const unsigned vw[4] = {vx.x, vx.y, vx.z, vx.w};
#pragma unroll
      for (int i = 0; i < 8; ++i) {
        const int h = hs*8 + i;
        const u16 val = (u16)(vw[i>>1] >> ((i&1)*16));
        *(u16*)((char*)&Vt[h*192] + ((m*2) ^ (((h>>3)&7)<<4))) = val;
      }
    }
  }

  // ---- Q fragments (B-operand): lane&15 = l, k = h; head = kh*8+g ----
  bf16x8 qb[4][2];
  {
    const u16* qbase = qkv + ((size_t)(b*TL + l0)*5120 + (kh*8 + g)*64);
#pragma unroll
    for (int l4 = 0; l4 < 4; ++l4)
#pragma unroll
      for (int kk = 0; kk < 2; ++kk)
        qb[l4][kk] = *(const bf16x8*)(qbase + (size_t)(l4*16 + lL)*5120 + kk*32 + q*8);
  }
  const float sink = sinks[kh*8 + g];
  __syncthreads();

  float Mrun[4] = {-1e30f,-1e30f,-1e30f,-1e30f};
  float Dden[4] = {0.f,0.f,0.f,0.f};
  f32x4 oacc[4][4];
#pragma unroll
  for (int i = 0; i < 4; ++i)
#pragma unroll
    for (int j = 0; j < 4; ++j) oacc[i][j] = (f32x4){0.f,0.f,0.f,0.f};

  u16* Pw = &Pl[g][0];

  for (int c = 0; c < NC; ++c) {
    bf16x8 ka[2][2];
#pragma unroll
    for (int m2 = 0; m2 < 2; ++m2) {
      const int row = c*32 + m2*16 + lL;
#pragma unroll
      for (int kk = 0; kk < 2; ++kk)
        ka[m2][kk] = *(const bf16x8*)((char*)&Kl[row*64] +
                       ((kk*64 + q*16) ^ ((row&7)<<4)));
    }
    bf16x8 vb[4];
#pragma unroll
    for (int hf = 0; hf < 4; ++hf) {
      const int h = hf*16 + lL;
      vb[hf] = *(const bf16x8*)((char*)&Vt[h*192] +
                 ((c*64 + q*16) ^ (((h>>3)&7)<<4)));
    }

#pragma unroll
    for (int l4 = 0; l4 < 4; ++l4) {
      const int lo = base + l4*16;
      if (c*32 > lo + 15 || c*32 + 31 < lo - 127) continue;   // prune

      const f32x4 z = (f32x4){0.f,0.f,0.f,0.f};
      f32x4 s0 = __builtin_amdgcn_mfma_f32_16x16x32_bf16(ka[0][0], qb[l4][0], z, 0,0,0);
      s0 = __builtin_amdgcn_mfma_f32_16x16x32_bf16(ka[0][1], qb[l4][1], s0, 0,0,0);
      f32x4 s1 = __builtin_amdgcn_mfma_f32_16x16x32_bf16(ka[1][0], qb[l4][0], z, 0,0,0);
      s1 = __builtin_amdgcn_mfma_f32_16x16x32_bf16(ka[1][1], qb[l4][1], s1, 0,0,0);

      float sv[2][4];
      bool  al[2][4];
      float cmax = -1e30f;
#pragma unroll
      for (int m2 = 0; m2 < 2; ++m2)
#pragma unroll
        for (int j = 0; j < 4; ++j) {
          const int delta = (lo + lL) - (c*32 + m2*16 + q*4 + j);
          const bool a = (delta >= 0) && (delta < TWIN);
          const float s = (m2 ? s1[j] : s0[j]);
          sv[m2][j] = s;
          al[m2][j] = a;
          if (a) cmax = fmaxf(cmax, s);
        }
      cmax = fmaxf(cmax, __shfl_xor(cmax, 16));
      cmax = fmaxf(cmax, __shfl_xor(cmax, 32));
      const float Mn = fmaxf(Mrun[l4], cmax);
      const float r = __expf(Mrun[l4] - Mn);
      Mrun[l4] = Mn;

      float ls = 0.f;
      u16 pb[2][4];
#pragma unroll
      for (int m2 = 0; m2 < 2; ++m2)
#pragma unroll
        for (int j = 0; j < 4; ++j) {
          const float p = al[m2][j] ? __expf(sv[m2][j] - Mn) : 0.f;
          ls += p;
          pb[m2][j] = f2b(p);
        }
      ls += __shfl_xor(ls, 16);
      ls += __shfl_xor(ls, 32);
      Dden[l4] = Dden[l4]*r + ls;

      const int l = l4*16 + lL;
#pragma unroll
      for (int m2 = 0; m2 < 2; ++m2) {
        uint2 w;
        w.x = (unsigned)pb[m2][0] | ((unsigned)pb[m2][1] << 16);
        w.y = (unsigned)pb[m2][2] | ((unsigned)pb[m2][3] << 16);
        *(uint2*)((char*)Pw + l*64 + ((m2*32 + q*8) ^ ((l&3)<<4))) = w;
      }

      float rb[4];
#pragma unroll
      for (int j = 0; j < 4; ++j) rb[j] = __shfl(r, q*4 + j);
#pragma unroll
      for (int hf = 0; hf < 4; ++hf)
#pragma unroll
        for (int j = 0; j < 4; ++j) oacc[l4][hf][j] *= rb[j];

      bf16x8 pa = *(const bf16x8*)((char*)Pw + l*64 + ((q*16) ^ ((l&3)<<4)));
#pragma unroll
      for (int hf = 0; hf < 4; ++hf)
        oacc[l4][hf] = __builtin_amdgcn_mfma_f32_16x16x32_bf16(
            pa, vb[hf], oacc[l4][hf], 0, 0, 0);
    }
  }

  // ---- epilogue: head column (kh*8+g)*64 ----
#pragma unroll
  for (int l4 = 0; l4 < 4; ++l4) {
    const float di = 1.0f / (Dden[l4] + __expf(sink - Mrun[l4]));
    float db[4];
#pragma unroll
    for (int j = 0; j < 4; ++j) db[j] = __shfl(di, q*4 + j);
#pragma unroll
    for (int hf = 0; hf < 4; ++hf)
#pragma unroll
      for (int j = 0; j < 4; ++j) {
        const int row = l0 + l4*16 + q*4 + j;
        obuf[(size_t)(b*TL + row)*4096 + (kh*8 + g)*64 + hf*16 + lL] =
            f2b(oacc[l4][hf][j] * db[j]);
      }
  }
}

// ---------------------------------------------------------------------------
extern "C" void kernel_launch(void* const* d_in, const int* in_sizes, int n_in,
                              void* d_out, int out_size, void* d_ws, size_t ws_size,
                              hipStream_t stream)
{
  const float* x     = (const float*)d_in[0];
  const float* wq    = (const float*)d_in[1];
  const float* bq    = (const float*)d_in[2];
  const float* wk    = (const float*)d_in[3];
  const float* bk    = (const float*)d_in[4];
  const float* wv    = (const float*)d_in[5];
  const float* bv    = (const float*)d_in[6];
  const float* wo    = (const float*)d_in[7];
  const float* bo    = (const float*)d_in[8];
  const float* sinks = (const float*)d_in[9];
  const int* positions = (const int*)d_in[10];
  float* out = (float*)d_out;

  u16* xb    = (u16*)d_ws;
  u16* wqkvt = xb + (size_t)TT*TD;
  u16* wot   = wqkvt + (size_t)5120*TD;
  u16* qkv   = wot + (size_t)2944*4096;
  u16* obuf  = qkv + (size_t)TT*5120;
  float* bqkv = (float*)(obuf + (size_t)TT*4096);

  cvt4_kernel<<<(TT*TD/4 + 255)/256, 256, 0, stream>>>(x, xb, TT*TD/4);
  tconv_kernel<<<dim3(128, 90), 256, 0, stream>>>(wq, wqkvt, TD, 4096);
  tconv_kernel<<<dim3(16, 90), 256, 0, stream>>>(wk, wqkvt + (size_t)4096*TD, TD, 512);
  tconv_kernel<<<dim3(16, 90), 256, 0, stream>>>(wv, wqkvt + (size_t)4608*TD, TD, 512);
  tconv_kernel<<<dim3(90, 128), 256, 0, stream>>>(wo, wot, 4096, TD);
  zerofill_kernel<<<(64*4096/4 + 255)/256, 256, 0, stream>>>(
      wot + (size_t)2880*4096, 64*4096/4);
  biascat_kernel<<<20, 256, 0, stream>>>(bq, bk, bv, bqkv);

  // fused QKV projection -> bf16 qkv [2048][5120]
  gemm_mfma<<<dim3(40, 16), 256, 0, stream>>>(
      xb, wqkvt, bqkv, qkv, TD, 5120, 5120, 1);

  // RoPE in place (q pre-scaled by SM_SCALE)
  rope_bf16_kernel<<<(TT*(TN+TKH)*32 + 255)/256, 256, 0, stream>>>(qkv, positions);

  // MFMA flash attention -> obuf [2048][4096]
  attn3_kernel<<<dim3(8, TKH, TB), 512, 0, stream>>>(qkv, obuf, sinks);

  // output projection -> fp32 out [2048][2880]
  gemm_mfma<<<dim3(23, 16), 256, 0, stream>>>(
      obuf, wot, bo, out, 4096, 2880, 2880, 0);
}

// Round 5
// 260.703 us; speedup vs baseline: 10.3798x; 1.0552x over previous
//
#include <hip/hip_runtime.h>
#include <hip/hip_bf16.h>

#define TB 4
#define TL 512
#define TD 2880
#define TN 64
#define TKH 8
#define TH 64
#define TG 8
#define TWIN 128
#define TT (TB*TL)

typedef unsigned short u16;
typedef __attribute__((ext_vector_type(8))) short bf16x8;
typedef __attribute__((ext_vector_type(4))) float f32x4;

__device__ __forceinline__ u16 f2b(float f) {
  unsigned u = __float_as_uint(f);
  u += 0x7fffu + ((u >> 16) & 1u);
  return (u16)(u >> 16);
}
__device__ __forceinline__ float b2f(u16 u) {
  return __uint_as_float(((unsigned)u) << 16);
}

__device__ __forceinline__ void load_lds16(const u16* g, u16* l) {
  __builtin_amdgcn_global_load_lds(
      (const __attribute__((address_space(1))) unsigned int*)g,
      (__attribute__((address_space(3))) unsigned int*)l, 16, 0, 0);
}

// ---------------------------------------------------------------------------
// Pipelined bf16 MFMA GEMM: C[M x Nc] = A * Bt^T + bias.
// 128x128 tile, BK=64, 4 waves (2x2, per-wave 64x64 = 4x4 frags).
// Double-buffered LDS, counted s_waitcnt vmcnt(8) (prefetch stays in flight
// across barriers — T3/T4), full 3-bit XOR swizzle on 128B rows (T2,
// involution on global source + ds_read addr), setprio around MFMA (T5).
// ---------------------------------------------------------------------------
__global__ __launch_bounds__(256) void gemm_pipe(
    const u16* __restrict__ A, const u16* __restrict__ Bt,
    const float* __restrict__ bias, void* __restrict__ Cv,
    int Kd, int Nc, int ldc, int out_bf16)
{
  // [buf][row 0..127][k 0..63] bf16, row stride 128 B
  __shared__ u16 As[2][128*64];
  __shared__ u16 Bs[2][128*64];

  const int tid  = threadIdx.x;
  const int lane = tid & 63;
  const int wave = tid >> 6;
  const int bm = blockIdx.y * 128, bn = blockIdx.x * 128;
  const int wr = (wave >> 1) * 64, wc = (wave & 1) * 64;

  f32x4 acc[4][4];
#pragma unroll
  for (int i = 0; i < 4; ++i)
#pragma unroll
    for (int j = 0; j < 4; ++j) acc[i][j] = (f32x4){0.f, 0.f, 0.f, 0.f};

  // Staging geometry: per issue, 256 threads cover 32 rows x 64 k (8 KB).
  // thread -> row = tid>>3 (within issue block), slot chunk = tid&7.
  // Source pre-swizzle (involution): slot c of row r holds global seg c^(r&7).
  const int rr   = tid >> 3;                      // 0..31
  const int sseg = (tid & 7) ^ (rr & 7);          // pre-swizzled k-seg
  const u16* aS = A  + (size_t)(bm + rr)*Kd + sseg*8;
  const u16* bS = Bt + (size_t)(bn + rr)*Kd + sseg*8;

#define STAGE(dA, dB, kt) do {                                         \
    const int _k0 = (kt) << 6;                                         \
    _Pragma("unroll")                                                  \
    for (int _i = 0; _i < 4; ++_i)                                     \
      load_lds16(aS + (size_t)_i*32*Kd + _k0, (dA) + _i*2048 + wave*512); \
    _Pragma("unroll")                                                  \
    for (int _i = 0; _i < 4; ++_i)                                     \
      load_lds16(bS + (size_t)_i*32*Kd + _k0, (dB) + _i*2048 + wave*512); \
  } while (0)

  const int NT = Kd >> 6;            // K-tiles of 64 (2880->45, 4096->64)
  const int fr = lane & 15, kq = lane >> 4;
  const int swz = lane & 7;          // row&7 == lane&7 for all frag rows

  STAGE(As[0], Bs[0], 0);

  for (int t = 0; t < NT; ++t) {
    const int c = t & 1;
    u16* Ac = As[c];  u16* Bc = Bs[c];
    u16* An = As[c ^ 1]; u16* Bn = Bs[c ^ 1];
    const int nk = (t + 1 < NT) ? (t + 1) : 0;   // last iter: dummy (unread)
    STAGE(An, Bn, nk);

    asm volatile("s_waitcnt vmcnt(8)" ::: "memory");  // my 8 loads for buf[c] done
    __builtin_amdgcn_s_barrier();                      // everyone's buf[c] ready
    __builtin_amdgcn_sched_barrier(0);

#pragma unroll
    for (int s = 0; s < 2; ++s) {
      const int ch = ((s*4 + kq) ^ swz) * 16;          // swizzled 16B chunk
      bf16x8 af[4], bv[4];
#pragma unroll
      for (int mi = 0; mi < 4; ++mi) {
        const int row = wr + mi*16 + fr;
        af[mi] = *(const bf16x8*)((const char*)&Ac[row*64] + ch);
      }
#pragma unroll
      for (int ni = 0; ni < 4; ++ni) {
        const int row = wc + ni*16 + fr;
        bv[ni] = *(const bf16x8*)((const char*)&Bc[row*64] + ch);
      }
      __builtin_amdgcn_s_setprio(1);
#pragma unroll
      for (int mi = 0; mi < 4; ++mi)
#pragma unroll
        for (int ni = 0; ni < 4; ++ni)
          acc[mi][ni] = __builtin_amdgcn_mfma_f32_16x16x32_bf16(
              af[mi], bv[ni], acc[mi][ni], 0, 0, 0);
      __builtin_amdgcn_s_setprio(0);
    }

    __builtin_amdgcn_s_barrier();                      // all reads of buf[c] done
    __builtin_amdgcn_sched_barrier(0);
  }
  asm volatile("s_waitcnt vmcnt(0)" ::: "memory");     // drain dummy prefetch
#undef STAGE

  // epilogue (verified R2/R4): C/D layout col=lane&15, row=(lane>>4)*4+j
  const int rbase = bm + wr + (lane >> 4) * 4;
  const int cbase = bn + wc + (lane & 15);
#pragma unroll
  for (int mi = 0; mi < 4; ++mi) {
#pragma unroll
    for (int ni = 0; ni < 4; ++ni) {
      const int col = cbase + ni*16;
      const float bv = (col < Nc) ? bias[col] : 0.f;
#pragma unroll
      for (int j = 0; j < 4; ++j) {
        const int row = rbase + mi*16 + j;
        const float val = acc[mi][ni][j] + bv;
        if (out_bf16) {
          ((u16*)Cv)[(size_t)row*ldc + col] = f2b(val);
        } else if (col < Nc) {
          ((float*)Cv)[(size_t)row*ldc + col] = val;
        }
      }
    }
  }
}

__global__ __launch_bounds__(256) void cvt4_kernel(
    const float* __restrict__ in, u16* __restrict__ out, int n4)
{
  int i = blockIdx.x*256 + threadIdx.x;
  if (i < n4) {
    float4 f = ((const float4*)in)[i];
    ushort4 o;
    o.x = f2b(f.x); o.y = f2b(f.y); o.z = f2b(f.z); o.w = f2b(f.w);
    ((ushort4*)out)[i] = o;
  }
}

__global__ __launch_bounds__(256) void tconv_kernel(
    const float* __restrict__ in, u16* __restrict__ out, int R, int C)
{
  __shared__ float tile[32][33];
  const int c0 = blockIdx.x*32, r0 = blockIdx.y*32;
  const int tx = threadIdx.x & 31, ty = threadIdx.x >> 5;
#pragma unroll
  for (int i = 0; i < 4; ++i)
    tile[ty + i*8][tx] = in[(size_t)(r0 + ty + i*8)*C + c0 + tx];
  __syncthreads();
#pragma unroll
  for (int i = 0; i < 4; ++i) {
    const int oc = ty + i*8;
    out[(size_t)(c0 + oc)*R + r0 + tx] = f2b(tile[tx][oc]);
  }
}

__global__ __launch_bounds__(256) void zerofill_kernel(u16* p, int n4)
{
  int i = blockIdx.x*256 + threadIdx.x;
  if (i < n4) ((ushort4*)p)[i] = (ushort4){0,0,0,0};
}

__global__ __launch_bounds__(256) void biascat_kernel(
    const float* __restrict__ bq, const float* __restrict__ bk,
    const float* __restrict__ bv, float* __restrict__ o)
{
  int i = blockIdx.x*256 + threadIdx.x;
  if (i < 5120)
    o[i] = (i < 4096) ? bq[i] : (i < 4608 ? bk[i-4096] : bv[i-4608]);
}

// ---------------------------------------------------------------------------
// YaRN RoPE in place on bf16 qkv [TT][5120]. SM_SCALE pre-folded into q.
// ---------------------------------------------------------------------------
__global__ __launch_bounds__(256) void rope_bf16_kernel(
    u16* __restrict__ qkv, const int* __restrict__ positions)
{
  const int total = TT*(TN+TKH)*32;
  int idx = blockIdx.x*256 + threadIdx.x;
  if (idx >= total) return;
  const int i    = idx & 31;
  const int rest = idx >> 5;
  const int head = rest % (TN+TKH);
  const int t    = rest / (TN+TKH);

  const float lnth = 11.918390573078392f;
  const float low  = 8.092779f;
  const float high = 17.398025f;
  const float conc = 1.3465735903f;

  const float fi = (float)i * 0.03125f;
  const float inv_theta_pow = __expf(-fi * lnth);
  const float interp = inv_theta_pow * (1.0f/32.0f);
  const float extrap = inv_theta_pow;
  float ramp = ((float)i - low) * (1.0f/(high - low));
  ramp = fminf(fmaxf(ramp, 0.0f), 1.0f);
  const float inv_freq = interp*ramp + extrap*(1.0f - ramp);

  const float ang = (float)positions[t] * inv_freq;
  const float mul = (head < TN) ? (conc * 0.125f) : conc;
  const float c = cosf(ang) * mul;
  const float s = sinf(ang) * mul;

  const int col = (head < TN) ? head*64 : 4096 + (head - TN)*64;
  u16* base = qkv + (size_t)t*5120 + col;
  const float x1 = b2f(base[i]);
  const float x2 = b2f(base[i + 32]);
  base[i]      = f2b(x1*c - x2*s);
  base[i + 32] = f2b(x2*c + x1*s);
}

// ---------------------------------------------------------------------------
// MFMA flash attention (verified R4). Block = (lt, kh, b), 8 waves = GQA head.
// ---------------------------------------------------------------------------
__global__ __launch_bounds__(512) void attn3_kernel(
    const u16* __restrict__ qkv, u16* __restrict__ obuf,
    const float* __restrict__ sinks)
{
  __shared__ u16 Kl[192*64];     // 24 KB
  __shared__ u16 Vt[64*192];     // 24 KB
  __shared__ u16 Pl[8][2048];    // 32 KB (per-wave 64l x 32m)

  const int lt = blockIdx.x, kh = blockIdx.y, b = blockIdx.z;
  const int l0 = lt*64;
  const int mstart = (l0 > 127) ? (l0 - 127) : 0;
  const int mcnt = l0 + 64 - mstart;          // <= 191
  const int NC = (mcnt + 31) >> 5;
  const int base = l0 - mstart;               // 0..127

  const int tid = threadIdx.x;
  const int lane = tid & 63;
  const int g = tid >> 6;
  const int lL = lane & 15;
  const int q = lane >> 4;

  {
    const u16* kv0 = qkv + ((size_t)(b*TL + mstart)*5120 + 4096 + kh*64);
    for (int s = tid; s < 1536; s += 512) {
      const int m = s >> 3, hs = s & 7;
      uint4 kx = make_uint4(0,0,0,0), vx = make_uint4(0,0,0,0);
      if (m < mcnt) {
        const u16* gp = kv0 + (size_t)m*5120 + hs*8;
        kx = *(const uint4*)gp;
        vx = *(const uint4*)(gp + 512);
      }
      *(uint4*)((char*)&Kl[m*64] + ((hs*16) ^ ((m&7)<<4))) = kx;
      const unsigned vw[4] = {vx.x, vx.y, vx.z, vx.w};
#pragma unroll
      for (int i = 0; i < 8; ++i) {
        const int h = hs*8 + i;
        const u16 val = (u16)(vw[i>>1] >> ((i&1)*16));
        *(u16*)((char*)&Vt[h*192] + ((m*2) ^ (((h>>3)&7)<<4))) = val;
      }
    }
  }

  bf16x8 qb[4][2];
  {
    const u16* qbase = qkv + ((size_t)(b*TL + l0)*5120 + (kh*8 + g)*64);
#pragma unroll
    for (int l4 = 0; l4 < 4; ++l4)
#pragma unroll
      for (int kk = 0; kk < 2; ++kk)
        qb[l4][kk] = *(const bf16x8*)(qbase + (size_t)(l4*16 + lL)*5120 + kk*32 + q*8);
  }
  const float sink = sinks[kh*8 + g];
  __syncthreads();

  float Mrun[4] = {-1e30f,-1e30f,-1e30f,-1e30f};
  float Dden[4] = {0.f,0.f,0.f,0.f};
  f32x4 oacc[4][4];
#pragma unroll
  for (int i = 0; i < 4; ++i)
#pragma unroll
    for (int j = 0; j < 4; ++j) oacc[i][j] = (f32x4){0.f,0.f,0.f,0.f};

  u16* Pw = &Pl[g][0];

  for (int c = 0; c < NC; ++c) {
    bf16x8 ka[2][2];
#pragma unroll
    for (int m2 = 0; m2 < 2; ++m2) {
      const int row = c*32 + m2*16 + lL;
#pragma unroll
      for (int kk = 0; kk < 2; ++kk)
        ka[m2][kk] = *(const bf16x8*)((char*)&Kl[row*64] +
                       ((kk*64 + q*16) ^ ((row&7)<<4)));
    }
    bf16x8 vb[4];
#pragma unroll
    for (int hf = 0; hf < 4; ++hf) {
      const int h = hf*16 + lL;
      vb[hf] = *(const bf16x8*)((char*)&Vt[h*192] +
                 ((c*64 + q*16) ^ (((h>>3)&7)<<4)));
    }

#pragma unroll
    for (int l4 = 0; l4 < 4; ++l4) {
      const int lo = base + l4*16;
      if (c*32 > lo + 15 || c*32 + 31 < lo - 127) continue;   // prune

      const f32x4 z = (f32x4){0.f,0.f,0.f,0.f};
      f32x4 s0 = __builtin_amdgcn_mfma_f32_16x16x32_bf16(ka[0][0], qb[l4][0], z, 0,0,0);
      s0 = __builtin_amdgcn_mfma_f32_16x16x32_bf16(ka[0][1], qb[l4][1], s0, 0,0,0);
      f32x4 s1 = __builtin_amdgcn_mfma_f32_16x16x32_bf16(ka[1][0], qb[l4][0], z, 0,0,0);
      s1 = __builtin_amdgcn_mfma_f32_16x16x32_bf16(ka[1][1], qb[l4][1], s1, 0,0,0);

      float sv[2][4];
      bool  al[2][4];
      float cmax = -1e30f;
#pragma unroll
      for (int m2 = 0; m2 < 2; ++m2)
#pragma unroll
        for (int j = 0; j < 4; ++j) {
          const int delta = (lo + lL) - (c*32 + m2*16 + q*4 + j);
          const bool a = (delta >= 0) && (delta < TWIN);
          const float s = (m2 ? s1[j] : s0[j]);
          sv[m2][j] = s;
          al[m2][j] = a;
          if (a) cmax = fmaxf(cmax, s);
        }
      cmax = fmaxf(cmax, __shfl_xor(cmax, 16));
      cmax = fmaxf(cmax, __shfl_xor(cmax, 32));
      const float Mn = fmaxf(Mrun[l4], cmax);
      const float r = __expf(Mrun[l4] - Mn);
      Mrun[l4] = Mn;

      float ls = 0.f;
      u16 pb[2][4];
#pragma unroll
      for (int m2 = 0; m2 < 2; ++m2)
#pragma unroll
        for (int j = 0; j < 4; ++j) {
          const float p = al[m2][j] ? __expf(sv[m2][j] - Mn) : 0.f;
          ls += p;
          pb[m2][j] = f2b(p);
        }
      ls += __shfl_xor(ls, 16);
      ls += __shfl_xor(ls, 32);
      Dden[l4] = Dden[l4]*r + ls;

      const int l = l4*16 + lL;
#pragma unroll
      for (int m2 = 0; m2 < 2; ++m2) {
        uint2 w;
        w.x = (unsigned)pb[m2][0] | ((unsigned)pb[m2][1] << 16);
        w.y = (unsigned)pb[m2][2] | ((unsigned)pb[m2][3] << 16);
        *(uint2*)((char*)Pw + l*64 + ((m2*32 + q*8) ^ ((l&3)<<4))) = w;
      }

      float rb[4];
#pragma unroll
      for (int j = 0; j < 4; ++j) rb[j] = __shfl(r, q*4 + j);
#pragma unroll
      for (int hf = 0; hf < 4; ++hf)
#pragma unroll
        for (int j = 0; j < 4; ++j) oacc[l4][hf][j] *= rb[j];

      bf16x8 pa = *(const bf16x8*)((char*)Pw + l*64 + ((q*16) ^ ((l&3)<<4)));
#pragma unroll
      for (int hf = 0; hf < 4; ++hf)
        oacc[l4][hf] = __builtin_amdgcn_mfma_f32_16x16x32_bf16(
            pa, vb[hf], oacc[l4][hf], 0, 0, 0);
    }
  }

#pragma unroll
  for (int l4 = 0; l4 < 4; ++l4) {
    const float di = 1.0f / (Dden[l4] + __expf(sink - Mrun[l4]));
    float db[4];
#pragma unroll
    for (int j = 0; j < 4; ++j) db[j] = __shfl(di, q*4 + j);
#pragma unroll
    for (int hf = 0; hf < 4; ++hf)
#pragma unroll
      for (int j = 0; j < 4; ++j) {
        const int row = l0 + l4*16 + q*4 + j;
        obuf[(size_t)(b*TL + row)*4096 + (kh*8 + g)*64 + hf*16 + lL] =
            f2b(oacc[l4][hf][j] * db[j]);
      }
  }
}

// ---------------------------------------------------------------------------
extern "C" void kernel_launch(void* const* d_in, const int* in_sizes, int n_in,
                              void* d_out, int out_size, void* d_ws, size_t ws_size,
                              hipStream_t stream)
{
  const float* x     = (const float*)d_in[0];
  const float* wq    = (const float*)d_in[1];
  const float* bq    = (const float*)d_in[2];
  const float* wk    = (const float*)d_in[3];
  const float* bk    = (const float*)d_in[4];
  const float* wv    = (const float*)d_in[5];
  const float* bv    = (const float*)d_in[6];
  const float* wo    = (const float*)d_in[7];
  const float* bo    = (const float*)d_in[8];
  const float* sinks = (const float*)d_in[9];
  const int* positions = (const int*)d_in[10];
  float* out = (float*)d_out;

  u16* xb    = (u16*)d_ws;
  u16* wqkvt = xb + (size_t)TT*TD;
  u16* wot   = wqkvt + (size_t)5120*TD;
  u16* qkv   = wot + (size_t)2944*4096;
  u16* obuf  = qkv + (size_t)TT*5120;
  float* bqkv = (float*)(obuf + (size_t)TT*4096);

  cvt4_kernel<<<(TT*TD/4 + 255)/256, 256, 0, stream>>>(x, xb, TT*TD/4);
  tconv_kernel<<<dim3(128, 90), 256, 0, stream>>>(wq, wqkvt, TD, 4096);
  tconv_kernel<<<dim3(16, 90), 256, 0, stream>>>(wk, wqkvt + (size_t)4096*TD, TD, 512);
  tconv_kernel<<<dim3(16, 90), 256, 0, stream>>>(wv, wqkvt + (size_t)4608*TD, TD, 512);
  tconv_kernel<<<dim3(90, 128), 256, 0, stream>>>(wo, wot, 4096, TD);
  zerofill_kernel<<<(64*4096/4 + 255)/256, 256, 0, stream>>>(
      wot + (size_t)2880*4096, 64*4096/4);
  biascat_kernel<<<20, 256, 0, stream>>>(bq, bk, bv, bqkv);

  // fused QKV projection -> bf16 qkv [2048][5120]
  gemm_pipe<<<dim3(40, 16), 256, 0, stream>>>(
      xb, wqkvt, bqkv, qkv, TD, 5120, 5120, 1);

  // RoPE in place (q pre-scaled by SM_SCALE)
  rope_bf16_kernel<<<(TT*(TN+TKH)*32 + 255)/256, 256, 0, stream>>>(qkv, positions);

  // MFMA flash attention -> obuf [2048][4096]
  attn3_kernel<<<dim3(8, TKH, TB), 512, 0, stream>>>(qkv, obuf, sinks);

  // output projection -> fp32 out [2048][2880]
  gemm_pipe<<<dim3(23, 16), 256, 0, stream>>>(
      obuf, wot, bo, out, 4096, 2880, 2880, 0);
}